// Round 9
// baseline (129.107 us; speedup 1.0000x reference)
//
#include <hip/hip_runtime.h>
#include <hip/hip_bf16.h>

typedef __attribute__((ext_vector_type(4))) float f32x4;
typedef __attribute__((ext_vector_type(8))) short s16x8;
typedef __attribute__((ext_vector_type(4))) short s16x4;

#define BB 2
#define NN 2048
#define HH 1024
#define NHEAD 16
#define HDIM 64

__device__ __forceinline__ short f2bf(float f) {
  union { float f; unsigned u; } v; v.f = f;
  unsigned r = v.u + 0x7fffu + ((v.u >> 16) & 1u);
  return (short)(r >> 16);
}

__device__ __forceinline__ f32x4 zf4() { f32x4 z; z[0]=0.f; z[1]=0.f; z[2]=0.f; z[3]=0.f; return z; }

__device__ __forceinline__ f32x4 mfma16(s16x8 a, s16x8 b, f32x4 c) {
  return __builtin_amdgcn_mfma_f32_16x16x32_bf16(a, b, c, 0, 0, 0);
}

__device__ __forceinline__ s16x4 cvt4(f32x4 v) {
  s16x4 o; o[0]=f2bf(v[0]); o[1]=f2bf(v[1]); o[2]=f2bf(v[2]); o[3]=f2bf(v[3]); return o;
}

__device__ __forceinline__ float vexp2(float x) {
  float r; asm("v_exp_f32 %0, %1" : "=v"(r) : "v"(x)); return r;
}

__device__ __forceinline__ float vrcp(float x) {
  float r; asm("v_rcp_f32 %0, %1" : "=v"(r) : "v"(x)); return r;
}

__device__ __forceinline__ float vmax3(float a, float b, float c) {
  float r; asm("v_max3_f32 %0, %1, %2, %3" : "=v"(r) : "v"(a), "v"(b), "v"(c)); return r;
}

__device__ __forceinline__ unsigned cvtpk_bf16(float lo, float hi) {
  unsigned r; asm("v_cvt_pk_bf16_f32 %0, %1, %2" : "=v"(r) : "v"(lo), "v"(hi)); return r;
}

// async global->LDS, 16B per lane; lds ptr must be wave-uniform base (HW adds lane*16)
__device__ __forceinline__ void gload_lds16(const short* g, short* l) {
  __builtin_amdgcn_global_load_lds(
      (const __attribute__((address_space(1))) unsigned*)g,
      (__attribute__((address_space(3))) unsigned*)l, 16, 0, 0);
}

// ---------------- prep: fp32->bf16 conversions + rope tables + mask bias ----------------
__global__ __launch_bounds__(256) void prep_kernel(
    const float* __restrict__ feat, const int* __restrict__ mask,
    const float* __restrict__ wq, const float* __restrict__ wk,
    const float* __restrict__ wv, const float* __restrict__ wo,
    short* __restrict__ fbf, short* __restrict__ wqb, short* __restrict__ wkb,
    short* __restrict__ wvb, short* __restrict__ wob,
    float* __restrict__ cosb, float* __restrict__ sinb,
    float* __restrict__ mbias, int* __restrict__ mseg) {
  const int tid = blockIdx.x * blockDim.x + threadIdx.x;
  const int nth = gridDim.x * blockDim.x;
  const int NF4 = BB*NN*HH/4;
  for (int i = tid; i < NF4; i += nth)
    ((s16x4*)fbf)[i] = cvt4(((const f32x4*)feat)[i]);
  const int NW4 = HH*HH/4;
  for (int i = tid; i < NW4; i += nth) {
    ((s16x4*)wqb)[i] = cvt4(((const f32x4*)wq)[i]);
    ((s16x4*)wkb)[i] = cvt4(((const f32x4*)wk)[i]);
    ((s16x4*)wvb)[i] = cvt4(((const f32x4*)wv)[i]);
    ((s16x4*)wob)[i] = cvt4(((const f32x4*)wo)[i]);
  }
  // rope table: cos/sin[pos][f], f in [0,32), inv_freq = 10000^(-f/32)
  for (int i = tid; i < NN*32; i += nth) {
    int pos = i >> 5, f = i & 31;
    float inv = __expf(-(float)f * 0.28782313662425572f);  // ln(10000)/32
    float ang = (float)pos * inv;
    float s, c;
    sincosf(ang, &s, &c);
    cosb[i] = c; sinb[i] = s;
  }
  // mask bias: 0 if valid, -1e30 if masked (finite so s-m never cancels to 0)
  for (int i = tid; i < BB*NN; i += nth)
    mbias[i] = mask[i] ? 0.f : -1.0e30f;
  // per-64-key segment flag: 1 if ANY key in segment is masked
  for (int i = tid; i < BB*(NN/64); i += nth) {
    int bb = i / (NN/64), sg = i % (NN/64);
    int any = 0;
    for (int j = 0; j < 64; ++j) any |= (mask[bb*NN + sg*64 + j] == 0);
    mseg[i] = any;
  }
}

// ---------------- GEMM core: C = A(bf16 [M,1024]) @ W^T ----------------
// 256 threads, tile 128x128, BK=32, waves 2x2, per-wave 64x64 (4x4 frags of 16x16x32)
// global_load_lds staging, double-buffered linear LDS
__device__ __forceinline__ void gemm128_core(
    const short* __restrict__ A, const short* __restrict__ W,
    int bm, int bn, short* smem, f32x4 acc[4][4]) {
  const int tid = threadIdx.x;
  const int lane = tid & 63, wid = tid >> 6;
  const int wr = wid >> 1, wc = wid & 1;
  const int g = lane >> 4, lr = lane & 15;
#pragma unroll
  for (int i = 0; i < 4; ++i)
#pragma unroll
    for (int j = 0; j < 4; ++j) acc[i][j] = zf4();

  const int srow = wid*16 + (lane >> 2);
  const int scol = (lane & 3) * 8;
  const short* Abase = A + (size_t)(bm*128 + srow)*HH + scol;
  const short* Wbase = W + (size_t)(bn*128 + srow)*HH + scol;

  auto stage = [&](int b, int t) {
    const short* ga = Abase + t*32;
    const short* gb = Wbase + t*32;
    short* la = smem + b*8192 + wid*512;          // wave-uniform LDS base
    short* lb = smem + b*8192 + 4096 + wid*512;
    gload_lds16(ga,          la);
    gload_lds16(ga + 64*HH,  la + 2048);
    gload_lds16(gb,          lb);
    gload_lds16(gb + 64*HH,  lb + 2048);
  };

  stage(0, 0);
  asm volatile("s_waitcnt vmcnt(0)");
  __syncthreads();

  const int NT = HH / 32;
  int cur = 0;
  for (int t = 0; t < NT; ++t) {
    if (t + 1 < NT) stage(cur ^ 1, t + 1);  // async loads overlap MFMA below
    const short* At = smem + cur*8192;
    const short* Bt = At + 4096;
    s16x8 af[4], bf[4];
#pragma unroll
    for (int mf = 0; mf < 4; ++mf)
      af[mf] = *(const s16x8*)&At[(wr*64 + mf*16 + lr)*32 + g*8];
#pragma unroll
    for (int nf = 0; nf < 4; ++nf)
      bf[nf] = *(const s16x8*)&Bt[(wc*64 + nf*16 + lr)*32 + g*8];
#pragma unroll
    for (int mf = 0; mf < 4; ++mf)
#pragma unroll
      for (int nf = 0; nf < 4; ++nf)
        acc[mf][nf] = mfma16(af[mf], bf[nf], acc[mf][nf]);
    __syncthreads();  // barrier drain completes the staged loads for next iter
    cur ^= 1;
  }
}

// ---------------- QKV projection + RoPE + layout ----------------
// z=0: Q (rope, *0.125*log2e) -> [b,h,n,d] ; z=1: K (rope) -> [b,h,n,d] ; z=2: V -> V^T [b,h,d,n]
__global__ __launch_bounds__(256) void qkv_kernel(
    const short* __restrict__ fbf, const short* __restrict__ wqb,
    const short* __restrict__ wkb, const short* __restrict__ wvb,
    const float* __restrict__ cosb, const float* __restrict__ sinb,
    short* __restrict__ qb, short* __restrict__ kb, short* __restrict__ vtb) {
  __shared__ short smem[18432];
  const int bm = blockIdx.y, bn = blockIdx.x, z = blockIdx.z;
  const short* W = (z == 0) ? wqb : ((z == 1) ? wkb : wvb);
  f32x4 acc[4][4];
  gemm128_core(fbf, W, bm, bn, smem, acc);

  const int tid = threadIdx.x, lane = tid & 63, wid = tid >> 6;
  const int wr = wid >> 1, wc = wid & 1, g = lane >> 4, lr = lane & 15;
  const int head = bn*2 + wc;
  const int m0 = bm*128 + wr*64;
  const int b = m0 / NN;

  if (z < 2) {
    short* dst = (z == 0) ? qb : kb;
    // Q: fold 1/sqrt(d) AND log2(e) (we use exp2 in attention)
    const float scale = (z == 0) ? 0.18033688011112042f : 1.0f;
#pragma unroll
    for (int mf = 0; mf < 4; ++mf) {
#pragma unroll
      for (int r = 0; r < 4; ++r) {
        int m = m0 + mf*16 + g*4 + r;
        int n = m & (NN - 1);
        float c0 = cosb[n*32 + lr],      s0 = sinb[n*32 + lr];
        float c1 = cosb[n*32 + 16 + lr], s1 = sinb[n*32 + 16 + lr];
        float v0 = acc[mf][0][r], v1 = acc[mf][1][r];
        float v2 = acc[mf][2][r], v3 = acc[mf][3][r];
        float o0 = (v0*c0 - v2*s0) * scale;
        float o1 = (v1*c1 - v3*s1) * scale;
        float o2 = (v2*c0 + v0*s0) * scale;
        float o3 = (v3*c1 + v1*s1) * scale;
        size_t base = ((size_t)(b*NHEAD + head)*NN + n)*HDIM;
        dst[base +  0 + lr] = f2bf(o0);
        dst[base + 16 + lr] = f2bf(o1);
        dst[base + 32 + lr] = f2bf(o2);
        dst[base + 48 + lr] = f2bf(o3);
      }
    }
  } else {
    __syncthreads();
    short* tp = smem + wid*4608;  // [64][72]
#pragma unroll
    for (int mf = 0; mf < 4; ++mf)
#pragma unroll
      for (int nf = 0; nf < 4; ++nf)
#pragma unroll
        for (int r = 0; r < 4; ++r)
          tp[(nf*16 + lr)*72 + mf*16 + g*4 + r] = f2bf(acc[mf][nf][r]);
    __syncthreads();
    const int nbase = m0 & (NN - 1);
    size_t vbase = ((size_t)(b*NHEAD + head)*HDIM)*NN;
#pragma unroll
    for (int it = 0; it < 8; ++it) {
      int j  = it*8 + (lane >> 3);
      int ns = (lane & 7)*8;
      s16x8 vv = *(const s16x8*)&tp[j*72 + ns];
      *(s16x8*)&vtb[vbase + (size_t)j*NN + nbase + ns] = vv;
    }
  }
}

// ---------------- fused flash attention ----------------
// Swapped QK^T + permuted K staging (P in registers) + ones-MFMA lsum + vcc-only defer-max.
// QBLK=256: each wave owns 64 q rows (4 q-groups); every K/V LDS fragment read serves all
// 4 groups -> LDS traffic per q-row is 1/4 of the QBLK=64 structure. 1 block/CU.
// XCD swizzle: bh = (w&7)*4 + ((w>>3)&3), qt = w>>5 -> all 8 q-tiles of a bh (and its
// 512KB K/V) live on one XCD; 4 bh x 512KB = 2MB fits the per-XCD L2.
// grid: 256 blocks; 4 waves; 64-key steps; K/V dbuf, 1 barrier/step.
__global__ __launch_bounds__(256, 1) void attn_kernel(
    const short* __restrict__ qb, const short* __restrict__ kb,
    const short* __restrict__ vtb, const float* __restrict__ mbias,
    const int* __restrict__ mseg,
    short* __restrict__ attnb) {
  __shared__ short Kt[2][64*72];   // [buf][perm key][64 d + pad]
  __shared__ short Vt[2][64*72];   // [buf][64 d][64 keys + pad]
  const int tid = threadIdx.x, lane = tid & 63, wid = tid >> 6;
  const int g = lane >> 4, lr = lane & 15;
  const int w = blockIdx.x;
  const int bh = (w & 7)*4 + ((w >> 3) & 3);
  const int qt = w >> 5;
  const int b = bh >> 4;
  const int q0 = qt*256 + wid*64;

  // Q regs for 4 q-groups (B-operand image: col=q=lr, k=d=g*8..+8)
  s16x8 qf[4][2];
#pragma unroll
  for (int grp = 0; grp < 4; ++grp) {
    const short* qp = qb + ((size_t)bh*NN + q0 + grp*16 + lr)*HDIM + g*8;
    qf[grp][0] = *(const s16x8*)(qp);
    qf[grp][1] = *(const s16x8*)(qp + 32);
  }

  s16x8 one8;
#pragma unroll
  for (int i = 0; i < 8; ++i) one8[i] = (short)0x3F80;  // bf16 1.0

  f32x4 acc[4][4];                 // [grp][db]
#pragma unroll
  for (int i = 0; i < 4; ++i)
#pragma unroll
    for (int j = 0; j < 4; ++j) acc[i][j] = zf4();
  f32x4 accl[4];
#pragma unroll
  for (int i = 0; i < 4; ++i) accl[i] = zf4();
  float mrun[4];
#pragma unroll
  for (int i = 0; i < 4; ++i) mrun[i] = -3.0e38f;

  // segment mask bitmask: bit sg = some key masked in segment sg (32 segments)
  const int* msp = mseg + b*(NN/64);
  int segflag = (lane < 32) ? msp[lane] : 0;
  unsigned segbits = (unsigned)__ballot(segflag != 0);

  const int sr = tid >> 2;            // staged row 0..63
  const int sc = (tid & 3) * 16;      // 0,16,32,48
  // permuted LDS row for K staging
  const int rK = ((sr >> 5) & 1)*32 + ((sr >> 2) & 1)*16 + ((sr >> 3) & 3)*4 + (sr & 3);
  const short* kp = kb + (size_t)bh*NN*HDIM + (size_t)sr*HDIM + sc;
  const short* vp = vtb + ((size_t)bh*HDIM + sr)*NN + sc;
  const float* mb = mbias + b*NN;

  // prologue: tile 0
  s16x8 kr0 = *(const s16x8*)(kp);
  s16x8 kr1 = *(const s16x8*)(kp + 8);
  s16x8 vr0 = *(const s16x8*)(vp);
  s16x8 vr1 = *(const s16x8*)(vp + 8);
  *(s16x8*)&Kt[0][rK*72 + sc]     = kr0;
  *(s16x8*)&Kt[0][rK*72 + sc + 8] = kr1;
  *(s16x8*)&Vt[0][sr*72 + sc]     = vr0;
  *(s16x8*)&Vt[0][sr*72 + sc + 8] = vr1;
  __syncthreads();

  int cur = 0;
  for (int k0 = 0; k0 < NN; k0 += 64) {
    const bool nl = (k0 + 64 < NN);
    if (nl) {  // issue next tile's global loads (latency hidden under compute)
      kp += 64*HDIM; vp += 64;
      kr0 = *(const s16x8*)(kp);
      kr1 = *(const s16x8*)(kp + 8);
      vr0 = *(const s16x8*)(vp);
      vr1 = *(const s16x8*)(vp + 8);
    }
    const short* KtC = Kt[cur];
    const short* VtC = Vt[cur];

    // S^T for all 4 q-groups, sharing each K fragment read
    f32x4 s[4][4];                 // [grp][j]
    __builtin_amdgcn_s_setprio(1);
#pragma unroll
    for (int j = 0; j < 4; ++j) {
      s16x8 ka0 = *(const s16x8*)&KtC[(j*16 + lr)*72 + g*8];
      s16x8 ka1 = *(const s16x8*)&KtC[(j*16 + lr)*72 + 32 + g*8];
#pragma unroll
      for (int grp = 0; grp < 4; ++grp)
        s[grp][j] = mfma16(ka1, qf[grp][1], mfma16(ka0, qf[grp][0], zf4()));
    }
    __builtin_amdgcn_s_setprio(0);

    if (segbits & (1u << (k0 >> 6))) {  // rare: some key in this segment masked
#pragma unroll
      for (int j = 0; j < 4; ++j) {
        f32x4 bi = *(const f32x4*)&mb[k0 + (j >> 1)*32 + (j & 1)*4 + g*8];
#pragma unroll
        for (int grp = 0; grp < 4; ++grp)
#pragma unroll
          for (int r = 0; r < 4; ++r) s[grp][j][r] += bi[r];
      }
    }

    // per-group softmax + pack (sequential so score regs die early)
    s16x8 pa[4][2];                // packed P fragments
#pragma unroll
    for (int grp = 0; grp < 4; ++grp) {
      float t0 = vmax3(s[grp][0][0], s[grp][0][1], s[grp][0][2]);
      float t1 = vmax3(s[grp][0][3], s[grp][1][0], s[grp][1][1]);
      float t2 = vmax3(s[grp][1][2], s[grp][1][3], s[grp][2][0]);
      float t3 = vmax3(s[grp][2][1], s[grp][2][2], s[grp][2][3]);
      float t4 = vmax3(s[grp][3][0], s[grp][3][1], s[grp][3][2]);
      float lmax = fmaxf(vmax3(t0, t1, t2), vmax3(t3, t4, s[grp][3][3]));

      if (__any(lmax > mrun[grp] + 8.f)) {
        float rmax = fmaxf(lmax, __shfl_xor(lmax, 16));
        rmax = fmaxf(rmax, __shfl_xor(rmax, 32));
        float mnew = fmaxf(mrun[grp], rmax);
        float al = vexp2(mrun[grp] - mnew);
        mrun[grp] = mnew;
        float alr[4];
#pragma unroll
        for (int r = 0; r < 4; ++r)
          alr[r] = __shfl(al, (lane & 48) | (g*4 + r));
#pragma unroll
        for (int r = 0; r < 4; ++r) {
          acc[grp][0][r] *= alr[r]; acc[grp][1][r] *= alr[r];
          acc[grp][2][r] *= alr[r]; acc[grp][3][r] *= alr[r];
          accl[grp][r]   *= alr[r];
        }
      }

      float p[4][4];
#pragma unroll
      for (int j = 0; j < 4; ++j) {
        p[j][0] = vexp2(s[grp][j][0] - mrun[grp]);
        p[j][1] = vexp2(s[grp][j][1] - mrun[grp]);
        p[j][2] = vexp2(s[grp][j][2] - mrun[grp]);
        p[j][3] = vexp2(s[grp][j][3] - mrun[grp]);
      }
      union { unsigned u[4]; s16x8 v; } P0, P1;
      P0.u[0] = cvtpk_bf16(p[0][0], p[0][1]);
      P0.u[1] = cvtpk_bf16(p[0][2], p[0][3]);
      P0.u[2] = cvtpk_bf16(p[1][0], p[1][1]);
      P0.u[3] = cvtpk_bf16(p[1][2], p[1][3]);
      P1.u[0] = cvtpk_bf16(p[2][0], p[2][1]);
      P1.u[1] = cvtpk_bf16(p[2][2], p[2][3]);
      P1.u[2] = cvtpk_bf16(p[3][0], p[3][1]);
      P1.u[3] = cvtpk_bf16(p[3][2], p[3][3]);
      pa[grp][0] = P0.v;
      pa[grp][1] = P1.v;
    }

    // PV + lsum-MFMA; each V fragment read feeds ALL 4 q-groups
    __builtin_amdgcn_s_setprio(1);
#pragma unroll
    for (int grp = 0; grp < 4; ++grp) {
      accl[grp] = mfma16(pa[grp][0], one8, accl[grp]);
      accl[grp] = mfma16(pa[grp][1], one8, accl[grp]);
    }
#pragma unroll
    for (int db = 0; db < 4; ++db) {
      s16x8 vb0 = *(const s16x8*)&VtC[(db*16 + lr)*72 + g*8];
      s16x8 vb1 = *(const s16x8*)&VtC[(db*16 + lr)*72 + 32 + g*8];
#pragma unroll
      for (int grp = 0; grp < 4; ++grp) {
        acc[grp][db] = mfma16(pa[grp][0], vb0, acc[grp][db]);
        acc[grp][db] = mfma16(pa[grp][1], vb1, acc[grp][db]);
      }
    }
    __builtin_amdgcn_s_setprio(0);

    if (nl) {  // write next tile into the other buffer; single barrier per step
      *(s16x8*)&Kt[cur^1][rK*72 + sc]     = kr0;
      *(s16x8*)&Kt[cur^1][rK*72 + sc + 8] = kr1;
      *(s16x8*)&Vt[cur^1][sr*72 + sc]     = vr0;
      *(s16x8*)&Vt[cur^1][sr*72 + sc + 8] = vr1;
      __syncthreads();
      cur ^= 1;
    }
  }

  // epilogue: 1/lsum already in C-layout for each group
#pragma unroll
  for (int grp = 0; grp < 4; ++grp) {
#pragma unroll
    for (int r = 0; r < 4; ++r) {
      float inv = vrcp(accl[grp][r]);
      size_t row = (size_t)(b*NN + q0 + grp*16 + g*4 + r);
#pragma unroll
      for (int db = 0; db < 4; ++db)
        attnb[row*HH + (bh & 15)*64 + db*16 + lr] = f2bf(acc[grp][db][r]*inv);
    }
  }
}

// ---------------- output projection (fp32 out) ----------------
__global__ __launch_bounds__(256) void outproj_kernel(
    const short* __restrict__ attnb, const short* __restrict__ wob,
    float* __restrict__ out) {
  __shared__ short smem[16384];
  const int bm = blockIdx.y, bn = blockIdx.x;
  f32x4 acc[4][4];
  gemm128_core(attnb, wob, bm, bn, smem, acc);
  const int tid = threadIdx.x, lane = tid & 63, wid = tid >> 6;
  const int wr = wid >> 1, wc = wid & 1, g = lane >> 4, lr = lane & 15;
  const int m0 = bm*128 + wr*64;
  const int c0 = bn*128 + wc*64;
#pragma unroll
  for (int mf = 0; mf < 4; ++mf)
#pragma unroll
    for (int r = 0; r < 4; ++r) {
      int m = m0 + mf*16 + g*4 + r;
      float* po = out + (size_t)m*HH + c0;
#pragma unroll
      for (int nf = 0; nf < 4; ++nf)
        po[nf*16 + lr] = acc[mf][nf][r];
    }
}

extern "C" void kernel_launch(void* const* d_in, const int* in_sizes, int n_in,
                              void* d_out, int out_size, void* d_ws, size_t ws_size,
                              hipStream_t stream) {
  const float* feat = (const float*)d_in[0];
  const int*   mask = (const int*)d_in[1];
  const float* wq   = (const float*)d_in[2];
  const float* wk   = (const float*)d_in[3];
  const float* wv   = (const float*)d_in[4];
  const float* wo   = (const float*)d_in[5];
  float* out = (float*)d_out;

  char* ws = (char*)d_ws;
  size_t off = 0;
  short* fbf = (short*)(ws + off); off += (size_t)BB*NN*HH*2;
  short* wqb = (short*)(ws + off); off += (size_t)HH*HH*2;
  short* wkb = (short*)(ws + off); off += (size_t)HH*HH*2;
  short* wvb = (short*)(ws + off); off += (size_t)HH*HH*2;
  short* wob = (short*)(ws + off); off += (size_t)HH*HH*2;
  float* cosb = (float*)(ws + off); off += (size_t)NN*32*4;
  float* sinb = (float*)(ws + off); off += (size_t)NN*32*4;
  float* mbias = (float*)(ws + off); off += (size_t)BB*NN*4;
  int* msegb = (int*)(ws + off); off += (size_t)BB*(NN/64)*4;
  short* qbuf = (short*)(ws + off); off += (size_t)BB*NN*HH*2;
  short* kbuf = (short*)(ws + off); off += (size_t)BB*NN*HH*2;
  short* vtbuf = (short*)(ws + off); off += (size_t)BB*NN*HH*2;
  short* attnb = (short*)(ws + off); off += (size_t)BB*NN*HH*2;

  prep_kernel<<<1024, 256, 0, stream>>>(feat, mask, wq, wk, wv, wo,
                                        fbf, wqb, wkb, wvb, wob, cosb, sinb,
                                        mbias, msegb);
  qkv_kernel<<<dim3(HH/128, BB*NN/128, 3), 256, 0, stream>>>(
      fbf, wqb, wkb, wvb, cosb, sinb, qbuf, kbuf, vtbuf);
  attn_kernel<<<256, 256, 0, stream>>>(
      qbuf, kbuf, vtbuf, mbias, msegb, attnb);
  outproj_kernel<<<dim3(HH/128, BB*NN/128), 256, 0, stream>>>(attnb, wob, out);
}

// Round 10
// 121.061 us; speedup vs baseline: 1.0665x; 1.0665x over previous
//
#include <hip/hip_runtime.h>
#include <hip/hip_bf16.h>

typedef __attribute__((ext_vector_type(4))) float f32x4;
typedef __attribute__((ext_vector_type(8))) short s16x8;
typedef __attribute__((ext_vector_type(4))) short s16x4;

#define BB 2
#define NN 2048
#define HH 1024
#define NHEAD 16
#define HDIM 64

__device__ __forceinline__ short f2bf(float f) {
  union { float f; unsigned u; } v; v.f = f;
  unsigned r = v.u + 0x7fffu + ((v.u >> 16) & 1u);
  return (short)(r >> 16);
}

__device__ __forceinline__ f32x4 zf4() { f32x4 z; z[0]=0.f; z[1]=0.f; z[2]=0.f; z[3]=0.f; return z; }

__device__ __forceinline__ f32x4 mfma16(s16x8 a, s16x8 b, f32x4 c) {
  return __builtin_amdgcn_mfma_f32_16x16x32_bf16(a, b, c, 0, 0, 0);
}

__device__ __forceinline__ s16x4 cvt4(f32x4 v) {
  s16x4 o; o[0]=f2bf(v[0]); o[1]=f2bf(v[1]); o[2]=f2bf(v[2]); o[3]=f2bf(v[3]); return o;
}

__device__ __forceinline__ float vexp2(float x) {
  float r; asm("v_exp_f32 %0, %1" : "=v"(r) : "v"(x)); return r;
}

__device__ __forceinline__ float vrcp(float x) {
  float r; asm("v_rcp_f32 %0, %1" : "=v"(r) : "v"(x)); return r;
}

__device__ __forceinline__ float vmax3(float a, float b, float c) {
  float r; asm("v_max3_f32 %0, %1, %2, %3" : "=v"(r) : "v"(a), "v"(b), "v"(c)); return r;
}

__device__ __forceinline__ unsigned cvtpk_bf16(float lo, float hi) {
  unsigned r; asm("v_cvt_pk_bf16_f32 %0, %1, %2" : "=v"(r) : "v"(lo), "v"(hi)); return r;
}

// async global->LDS, 16B per lane; lds ptr must be wave-uniform base (HW adds lane*16)
__device__ __forceinline__ void gload_lds16(const short* g, short* l) {
  __builtin_amdgcn_global_load_lds(
      (const __attribute__((address_space(1))) unsigned*)g,
      (__attribute__((address_space(3))) unsigned*)l, 16, 0, 0);
}

// ---------------- prep: fp32->bf16 conversions + rope tables + mask bias ----------------
__global__ __launch_bounds__(256) void prep_kernel(
    const float* __restrict__ feat, const int* __restrict__ mask,
    const float* __restrict__ wq, const float* __restrict__ wk,
    const float* __restrict__ wv, const float* __restrict__ wo,
    short* __restrict__ fbf, short* __restrict__ wqb, short* __restrict__ wkb,
    short* __restrict__ wvb, short* __restrict__ wob,
    float* __restrict__ cosb, float* __restrict__ sinb,
    float* __restrict__ mbias, int* __restrict__ mseg) {
  const int tid = blockIdx.x * blockDim.x + threadIdx.x;
  const int nth = gridDim.x * blockDim.x;
  const int NF4 = BB*NN*HH/4;
  for (int i = tid; i < NF4; i += nth)
    ((s16x4*)fbf)[i] = cvt4(((const f32x4*)feat)[i]);
  const int NW4 = HH*HH/4;
  for (int i = tid; i < NW4; i += nth) {
    ((s16x4*)wqb)[i] = cvt4(((const f32x4*)wq)[i]);
    ((s16x4*)wkb)[i] = cvt4(((const f32x4*)wk)[i]);
    ((s16x4*)wvb)[i] = cvt4(((const f32x4*)wv)[i]);
    ((s16x4*)wob)[i] = cvt4(((const f32x4*)wo)[i]);
  }
  // rope table: cos/sin[pos][f], f in [0,32), inv_freq = 10000^(-f/32)
  for (int i = tid; i < NN*32; i += nth) {
    int pos = i >> 5, f = i & 31;
    float inv = __expf(-(float)f * 0.28782313662425572f);  // ln(10000)/32
    float ang = (float)pos * inv;
    float s, c;
    sincosf(ang, &s, &c);
    cosb[i] = c; sinb[i] = s;
  }
  // mask bias: 0 if valid, -1e30 if masked (finite so s-m never cancels to 0)
  for (int i = tid; i < BB*NN; i += nth)
    mbias[i] = mask[i] ? 0.f : -1.0e30f;
  // per-64-key segment flag: 1 if ANY key in segment is masked
  for (int i = tid; i < BB*(NN/64); i += nth) {
    int bb = i / (NN/64), sg = i % (NN/64);
    int any = 0;
    for (int j = 0; j < 64; ++j) any |= (mask[bb*NN + sg*64 + j] == 0);
    mseg[i] = any;
  }
}

// ---------------- GEMM core: C = A(bf16 [M,1024]) @ W^T ----------------
// 256 threads, tile 128x128, BK=32, waves 2x2, per-wave 64x64 (4x4 frags of 16x16x32)
// global_load_lds staging, double-buffered linear LDS
__device__ __forceinline__ void gemm128_core(
    const short* __restrict__ A, const short* __restrict__ W,
    int bm, int bn, short* smem, f32x4 acc[4][4]) {
  const int tid = threadIdx.x;
  const int lane = tid & 63, wid = tid >> 6;
  const int wr = wid >> 1, wc = wid & 1;
  const int g = lane >> 4, lr = lane & 15;
#pragma unroll
  for (int i = 0; i < 4; ++i)
#pragma unroll
    for (int j = 0; j < 4; ++j) acc[i][j] = zf4();

  const int srow = wid*16 + (lane >> 2);
  const int scol = (lane & 3) * 8;
  const short* Abase = A + (size_t)(bm*128 + srow)*HH + scol;
  const short* Wbase = W + (size_t)(bn*128 + srow)*HH + scol;

  auto stage = [&](int b, int t) {
    const short* ga = Abase + t*32;
    const short* gb = Wbase + t*32;
    short* la = smem + b*8192 + wid*512;          // wave-uniform LDS base
    short* lb = smem + b*8192 + 4096 + wid*512;
    gload_lds16(ga,          la);
    gload_lds16(ga + 64*HH,  la + 2048);
    gload_lds16(gb,          lb);
    gload_lds16(gb + 64*HH,  lb + 2048);
  };

  stage(0, 0);
  asm volatile("s_waitcnt vmcnt(0)");
  __syncthreads();

  const int NT = HH / 32;
  int cur = 0;
  for (int t = 0; t < NT; ++t) {
    if (t + 1 < NT) stage(cur ^ 1, t + 1);  // async loads overlap MFMA below
    const short* At = smem + cur*8192;
    const short* Bt = At + 4096;
    s16x8 af[4], bf[4];
#pragma unroll
    for (int mf = 0; mf < 4; ++mf)
      af[mf] = *(const s16x8*)&At[(wr*64 + mf*16 + lr)*32 + g*8];
#pragma unroll
    for (int nf = 0; nf < 4; ++nf)
      bf[nf] = *(const s16x8*)&Bt[(wc*64 + nf*16 + lr)*32 + g*8];
#pragma unroll
    for (int mf = 0; mf < 4; ++mf)
#pragma unroll
      for (int nf = 0; nf < 4; ++nf)
        acc[mf][nf] = mfma16(af[mf], bf[nf], acc[mf][nf]);
    __syncthreads();  // barrier drain completes the staged loads for next iter
    cur ^= 1;
  }
}

// ---------------- QKV projection + RoPE + layout ----------------
// z=0: Q (rope, *0.125*log2e) -> [b,h,n,d] ; z=1: K (rope) -> [b,h,n,d] ; z=2: V -> V^T [b,h,d,n]
__global__ __launch_bounds__(256) void qkv_kernel(
    const short* __restrict__ fbf, const short* __restrict__ wqb,
    const short* __restrict__ wkb, const short* __restrict__ wvb,
    const float* __restrict__ cosb, const float* __restrict__ sinb,
    short* __restrict__ qb, short* __restrict__ kb, short* __restrict__ vtb) {
  __shared__ short smem[18432];
  const int bm = blockIdx.y, bn = blockIdx.x, z = blockIdx.z;
  const short* W = (z == 0) ? wqb : ((z == 1) ? wkb : wvb);
  f32x4 acc[4][4];
  gemm128_core(fbf, W, bm, bn, smem, acc);

  const int tid = threadIdx.x, lane = tid & 63, wid = tid >> 6;
  const int wr = wid >> 1, wc = wid & 1, g = lane >> 4, lr = lane & 15;
  const int head = bn*2 + wc;
  const int m0 = bm*128 + wr*64;
  const int b = m0 / NN;

  if (z < 2) {
    short* dst = (z == 0) ? qb : kb;
    // Q: fold 1/sqrt(d) AND log2(e) (we use exp2 in attention)
    const float scale = (z == 0) ? 0.18033688011112042f : 1.0f;
#pragma unroll
    for (int mf = 0; mf < 4; ++mf) {
#pragma unroll
      for (int r = 0; r < 4; ++r) {
        int m = m0 + mf*16 + g*4 + r;
        int n = m & (NN - 1);
        float c0 = cosb[n*32 + lr],      s0 = sinb[n*32 + lr];
        float c1 = cosb[n*32 + 16 + lr], s1 = sinb[n*32 + 16 + lr];
        float v0 = acc[mf][0][r], v1 = acc[mf][1][r];
        float v2 = acc[mf][2][r], v3 = acc[mf][3][r];
        float o0 = (v0*c0 - v2*s0) * scale;
        float o1 = (v1*c1 - v3*s1) * scale;
        float o2 = (v2*c0 + v0*s0) * scale;
        float o3 = (v3*c1 + v1*s1) * scale;
        size_t base = ((size_t)(b*NHEAD + head)*NN + n)*HDIM;
        dst[base +  0 + lr] = f2bf(o0);
        dst[base + 16 + lr] = f2bf(o1);
        dst[base + 32 + lr] = f2bf(o2);
        dst[base + 48 + lr] = f2bf(o3);
      }
    }
  } else {
    __syncthreads();
    short* tp = smem + wid*4608;  // [64][72]
#pragma unroll
    for (int mf = 0; mf < 4; ++mf)
#pragma unroll
      for (int nf = 0; nf < 4; ++nf)
#pragma unroll
        for (int r = 0; r < 4; ++r)
          tp[(nf*16 + lr)*72 + mf*16 + g*4 + r] = f2bf(acc[mf][nf][r]);
    __syncthreads();
    const int nbase = m0 & (NN - 1);
    size_t vbase = ((size_t)(b*NHEAD + head)*HDIM)*NN;
#pragma unroll
    for (int it = 0; it < 8; ++it) {
      int j  = it*8 + (lane >> 3);
      int ns = (lane & 7)*8;
      s16x8 vv = *(const s16x8*)&tp[j*72 + ns];
      *(s16x8*)&vtb[vbase + (size_t)j*NN + nbase + ns] = vv;
    }
  }
}

// ---------------- fused flash attention ----------------
// Round-8 structure (QBLK=128, 32 q/wave, 2 q-groups, 2 waves/SIMD) +
//  - bijective XCD-pinned swizzle: w = xcd(3b) | sub(2b) | qt(4b); bh = xcd*4+sub.
//    All 16 q-tiles of a bh stay on one XCD -> its 512KB K/V is L2-resident (4bh/XCD = 2MB).
//  - early staging writes: next-tile ds_writes issued BEFORE the PV MFMA cluster
//    (they target buf^1 while PV reads buf — race-free inside the barrier-synced step),
//    hiding ds_write + k/v vmcnt latency under 20 MFMAs.
// grid: 512 blocks; 4 waves; 64-key steps; K/V dbuf, 1 barrier/step.
__global__ __launch_bounds__(256) void attn_kernel(
    const short* __restrict__ qb, const short* __restrict__ kb,
    const short* __restrict__ vtb, const float* __restrict__ mbias,
    const int* __restrict__ mseg,
    short* __restrict__ attnb) {
  __shared__ short Kt[2][64*72];   // [buf][perm key][64 d + pad]
  __shared__ short Vt[2][64*72];   // [buf][64 d][64 keys + pad]
  const int tid = threadIdx.x, lane = tid & 63, wid = tid >> 6;
  const int g = lane >> 4, lr = lane & 15;
  const int w = blockIdx.x;
  const int bh = (w & 7)*4 + ((w >> 3) & 3);
  const int qt = w >> 5;
  const int b = bh >> 4;
  const int q0 = qt*128 + wid*32;

  // Q regs for both q-groups (B-operand image: col=q=lr, k=d=g*8..+8)
  const short* qpA = qb + ((size_t)bh*NN + q0 + lr)*HDIM + g*8;
  s16x8 qfA0 = *(const s16x8*)(qpA);
  s16x8 qfA1 = *(const s16x8*)(qpA + 32);
  const short* qpB = qpA + 16*HDIM;
  s16x8 qfB0 = *(const s16x8*)(qpB);
  s16x8 qfB1 = *(const s16x8*)(qpB + 32);

  s16x8 one8;
#pragma unroll
  for (int i = 0; i < 8; ++i) one8[i] = (short)0x3F80;  // bf16 1.0

  f32x4 accA[4], accB[4];
#pragma unroll
  for (int i = 0; i < 4; ++i) { accA[i] = zf4(); accB[i] = zf4(); }
  f32x4 acclA = zf4(), acclB = zf4();
  float mrunA = -3.0e38f, mrunB = -3.0e38f;

  // segment mask bitmask: bit sg = some key masked in segment sg (32 segments)
  const int* msp = mseg + b*(NN/64);
  int segflag = (lane < 32) ? msp[lane] : 0;
  unsigned segbits = (unsigned)__ballot(segflag != 0);

  const int sr = tid >> 2;            // staged row 0..63
  const int sc = (tid & 3) * 16;      // 0,16,32,48
  // permuted LDS row for K staging
  const int rK = ((sr >> 5) & 1)*32 + ((sr >> 2) & 1)*16 + ((sr >> 3) & 3)*4 + (sr & 3);
  const short* kp = kb + (size_t)bh*NN*HDIM + (size_t)sr*HDIM + sc;
  const short* vp = vtb + ((size_t)bh*HDIM + sr)*NN + sc;
  const float* mb = mbias + b*NN;

  // prologue: tile 0
  s16x8 kr0 = *(const s16x8*)(kp);
  s16x8 kr1 = *(const s16x8*)(kp + 8);
  s16x8 vr0 = *(const s16x8*)(vp);
  s16x8 vr1 = *(const s16x8*)(vp + 8);
  *(s16x8*)&Kt[0][rK*72 + sc]     = kr0;
  *(s16x8*)&Kt[0][rK*72 + sc + 8] = kr1;
  *(s16x8*)&Vt[0][sr*72 + sc]     = vr0;
  *(s16x8*)&Vt[0][sr*72 + sc + 8] = vr1;
  __syncthreads();

  int cur = 0;
  for (int k0 = 0; k0 < NN; k0 += 64) {
    const bool nl = (k0 + 64 < NN);
    if (nl) {  // issue next tile's global loads (L2-resident via XCD pinning)
      kp += 64*HDIM; vp += 64;
      kr0 = *(const s16x8*)(kp);
      kr1 = *(const s16x8*)(kp + 8);
      vr0 = *(const s16x8*)(vp);
      vr1 = *(const s16x8*)(vp + 8);
    }
    const short* KtC = Kt[cur];
    const short* VtC = Vt[cur];

    // S^T for both q-groups, sharing each K fragment read
    f32x4 sA[4], sB[4];
    __builtin_amdgcn_s_setprio(1);
#pragma unroll
    for (int j = 0; j < 4; ++j) {
      s16x8 ka0 = *(const s16x8*)&KtC[(j*16 + lr)*72 + g*8];
      s16x8 ka1 = *(const s16x8*)&KtC[(j*16 + lr)*72 + 32 + g*8];
      sA[j] = mfma16(ka1, qfA1, mfma16(ka0, qfA0, zf4()));
      sB[j] = mfma16(ka1, qfB1, mfma16(ka0, qfB0, zf4()));
    }
    __builtin_amdgcn_s_setprio(0);

    if (segbits & (1u << (k0 >> 6))) {  // rare: some key in this segment masked
#pragma unroll
      for (int j = 0; j < 4; ++j) {
        f32x4 bi = *(const f32x4*)&mb[k0 + (j >> 1)*32 + (j & 1)*4 + g*8];
#pragma unroll
        for (int r = 0; r < 4; ++r) { sA[j][r] += bi[r]; sB[j][r] += bi[r]; }
      }
    }

    // lane-local max trees
    float a0 = vmax3(sA[0][0], sA[0][1], sA[0][2]);
    float a1 = vmax3(sA[0][3], sA[1][0], sA[1][1]);
    float a2 = vmax3(sA[1][2], sA[1][3], sA[2][0]);
    float a3 = vmax3(sA[2][1], sA[2][2], sA[2][3]);
    float a4 = vmax3(sA[3][0], sA[3][1], sA[3][2]);
    float lmaxA = fmaxf(vmax3(a0, a1, a2), vmax3(a3, a4, sA[3][3]));
    float b0 = vmax3(sB[0][0], sB[0][1], sB[0][2]);
    float b1 = vmax3(sB[0][3], sB[1][0], sB[1][1]);
    float b2 = vmax3(sB[1][2], sB[1][3], sB[2][0]);
    float b3 = vmax3(sB[2][1], sB[2][2], sB[2][3]);
    float b4 = vmax3(sB[3][0], sB[3][1], sB[3][2]);
    float lmaxB = fmaxf(vmax3(b0, b1, b2), vmax3(b3, b4, sB[3][3]));

    // defer-max: vcc-only checks; full reduce+rescale only on (rare) trigger
    if (__any(lmaxA > mrunA + 8.f)) {
      float rmax = fmaxf(lmaxA, __shfl_xor(lmaxA, 16));
      rmax = fmaxf(rmax, __shfl_xor(rmax, 32));
      float mnew = fmaxf(mrunA, rmax);
      float al = vexp2(mrunA - mnew);
      mrunA = mnew;
      float alr[4];
#pragma unroll
      for (int r = 0; r < 4; ++r)
        alr[r] = __shfl(al, (lane & 48) | (g*4 + r));
#pragma unroll
      for (int r = 0; r < 4; ++r) {
        accA[0][r] *= alr[r]; accA[1][r] *= alr[r];
        accA[2][r] *= alr[r]; accA[3][r] *= alr[r];
        acclA[r]   *= alr[r];
      }
    }
    if (__any(lmaxB > mrunB + 8.f)) {
      float rmax = fmaxf(lmaxB, __shfl_xor(lmaxB, 16));
      rmax = fmaxf(rmax, __shfl_xor(rmax, 32));
      float mnew = fmaxf(mrunB, rmax);
      float al = vexp2(mrunB - mnew);
      mrunB = mnew;
      float alr[4];
#pragma unroll
      for (int r = 0; r < 4; ++r)
        alr[r] = __shfl(al, (lane & 48) | (g*4 + r));
#pragma unroll
      for (int r = 0; r < 4; ++r) {
        accB[0][r] *= alr[r]; accB[1][r] *= alr[r];
        accB[2][r] *= alr[r]; accB[3][r] *= alr[r];
        acclB[r]   *= alr[r];
      }
    }

    // p = 2^(s - m); pack in-lane -> PV A-frags in regs
    union { unsigned u[4]; s16x8 v; } A0, A1, B0, B1;
    {
      float p[4][4];
#pragma unroll
      for (int j = 0; j < 4; ++j) {
        p[j][0] = vexp2(sA[j][0] - mrunA);
        p[j][1] = vexp2(sA[j][1] - mrunA);
        p[j][2] = vexp2(sA[j][2] - mrunA);
        p[j][3] = vexp2(sA[j][3] - mrunA);
      }
      A0.u[0] = cvtpk_bf16(p[0][0], p[0][1]);
      A0.u[1] = cvtpk_bf16(p[0][2], p[0][3]);
      A0.u[2] = cvtpk_bf16(p[1][0], p[1][1]);
      A0.u[3] = cvtpk_bf16(p[1][2], p[1][3]);
      A1.u[0] = cvtpk_bf16(p[2][0], p[2][1]);
      A1.u[1] = cvtpk_bf16(p[2][2], p[2][3]);
      A1.u[2] = cvtpk_bf16(p[3][0], p[3][1]);
      A1.u[3] = cvtpk_bf16(p[3][2], p[3][3]);
    }
    {
      float p[4][4];
#pragma unroll
      for (int j = 0; j < 4; ++j) {
        p[j][0] = vexp2(sB[j][0] - mrunB);
        p[j][1] = vexp2(sB[j][1] - mrunB);
        p[j][2] = vexp2(sB[j][2] - mrunB);
        p[j][3] = vexp2(sB[j][3] - mrunB);
      }
      B0.u[0] = cvtpk_bf16(p[0][0], p[0][1]);
      B0.u[1] = cvtpk_bf16(p[0][2], p[0][3]);
      B0.u[2] = cvtpk_bf16(p[1][0], p[1][1]);
      B0.u[3] = cvtpk_bf16(p[1][2], p[1][3]);
      B1.u[0] = cvtpk_bf16(p[2][0], p[2][1]);
      B1.u[1] = cvtpk_bf16(p[2][2], p[2][3]);
      B1.u[2] = cvtpk_bf16(p[3][0], p[3][1]);
      B1.u[3] = cvtpk_bf16(p[3][2], p[3][3]);
    }

    // EARLY staging writes: target buf^1 (PV below reads buf) — latency hides under PV
    if (nl) {
      *(s16x8*)&Kt[cur^1][rK*72 + sc]     = kr0;
      *(s16x8*)&Kt[cur^1][rK*72 + sc + 8] = kr1;
      *(s16x8*)&Vt[cur^1][sr*72 + sc]     = vr0;
      *(s16x8*)&Vt[cur^1][sr*72 + sc + 8] = vr1;
    }

    // PV + lsum-MFMA; each V fragment read feeds BOTH q-groups
    __builtin_amdgcn_s_setprio(1);
    acclA = mfma16(A0.v, one8, acclA);
    acclA = mfma16(A1.v, one8, acclA);
    acclB = mfma16(B0.v, one8, acclB);
    acclB = mfma16(B1.v, one8, acclB);
#pragma unroll
    for (int db = 0; db < 4; ++db) {
      s16x8 vb0 = *(const s16x8*)&VtC[(db*16 + lr)*72 + g*8];
      s16x8 vb1 = *(const s16x8*)&VtC[(db*16 + lr)*72 + 32 + g*8];
      accA[db] = mfma16(A0.v, vb0, accA[db]);
      accA[db] = mfma16(A1.v, vb1, accA[db]);
      accB[db] = mfma16(B0.v, vb0, accB[db]);
      accB[db] = mfma16(B1.v, vb1, accB[db]);
    }
    __builtin_amdgcn_s_setprio(0);

    if (nl) {
      __syncthreads();
      cur ^= 1;
    }
  }

  // epilogue: 1/lsum already in C-layout for each group
#pragma unroll
  for (int r = 0; r < 4; ++r) {
    float invA = vrcp(acclA[r]);
    float invB = vrcp(acclB[r]);
    size_t rowA = (size_t)(b*NN + q0 + g*4 + r);
    size_t rowB = rowA + 16;
#pragma unroll
    for (int db = 0; db < 4; ++db) {
      attnb[rowA*HH + (bh & 15)*64 + db*16 + lr] = f2bf(accA[db][r]*invA);
      attnb[rowB*HH + (bh & 15)*64 + db*16 + lr] = f2bf(accB[db][r]*invB);
    }
  }
}

// ---------------- output projection (fp32 out) ----------------
__global__ __launch_bounds__(256) void outproj_kernel(
    const short* __restrict__ attnb, const short* __restrict__ wob,
    float* __restrict__ out) {
  __shared__ short smem[16384];
  const int bm = blockIdx.y, bn = blockIdx.x;
  f32x4 acc[4][4];
  gemm128_core(attnb, wob, bm, bn, smem, acc);
  const int tid = threadIdx.x, lane = tid & 63, wid = tid >> 6;
  const int wr = wid >> 1, wc = wid & 1, g = lane >> 4, lr = lane & 15;
  const int m0 = bm*128 + wr*64;
  const int c0 = bn*128 + wc*64;
#pragma unroll
  for (int mf = 0; mf < 4; ++mf)
#pragma unroll
    for (int r = 0; r < 4; ++r) {
      int m = m0 + mf*16 + g*4 + r;
      float* po = out + (size_t)m*HH + c0;
#pragma unroll
      for (int nf = 0; nf < 4; ++nf)
        po[nf*16 + lr] = acc[mf][nf][r];
    }
}

extern "C" void kernel_launch(void* const* d_in, const int* in_sizes, int n_in,
                              void* d_out, int out_size, void* d_ws, size_t ws_size,
                              hipStream_t stream) {
  const float* feat = (const float*)d_in[0];
  const int*   mask = (const int*)d_in[1];
  const float* wq   = (const float*)d_in[2];
  const float* wk   = (const float*)d_in[3];
  const float* wv   = (const float*)d_in[4];
  const float* wo   = (const float*)d_in[5];
  float* out = (float*)d_out;

  char* ws = (char*)d_ws;
  size_t off = 0;
  short* fbf = (short*)(ws + off); off += (size_t)BB*NN*HH*2;
  short* wqb = (short*)(ws + off); off += (size_t)HH*HH*2;
  short* wkb = (short*)(ws + off); off += (size_t)HH*HH*2;
  short* wvb = (short*)(ws + off); off += (size_t)HH*HH*2;
  short* wob = (short*)(ws + off); off += (size_t)HH*HH*2;
  float* cosb = (float*)(ws + off); off += (size_t)NN*32*4;
  float* sinb = (float*)(ws + off); off += (size_t)NN*32*4;
  float* mbias = (float*)(ws + off); off += (size_t)BB*NN*4;
  int* msegb = (int*)(ws + off); off += (size_t)BB*(NN/64)*4;
  short* qbuf = (short*)(ws + off); off += (size_t)BB*NN*HH*2;
  short* kbuf = (short*)(ws + off); off += (size_t)BB*NN*HH*2;
  short* vtbuf = (short*)(ws + off); off += (size_t)BB*NN*HH*2;
  short* attnb = (short*)(ws + off); off += (size_t)BB*NN*HH*2;

  prep_kernel<<<1024, 256, 0, stream>>>(feat, mask, wq, wk, wv, wo,
                                        fbf, wqb, wkb, wvb, wob, cosb, sinb,
                                        mbias, msegb);
  qkv_kernel<<<dim3(HH/128, BB*NN/128, 3), 256, 0, stream>>>(
      fbf, wqb, wkb, wvb, cosb, sinb, qbuf, kbuf, vtbuf);
  attn_kernel<<<512, 256, 0, stream>>>(
      qbuf, kbuf, vtbuf, mbias, msegb, attnb);
  outproj_kernel<<<dim3(HH/128, BB*NN/128), 256, 0, stream>>>(attnb, wob, out);
}